// Round 1
// baseline (23010.570 us; speedup 1.0000x reference)
//
#include <hip/hip_runtime.h>
#include <hip/hip_bf16.h>

#define N_NODES 100000
#define N_EDGES 1600000

// ---- RK45 (Dormand-Prince) coefficients, fp32 ----
#define Hc   0.1f
#define A21c 0.2f
#define A31c (float)(3.0/40.0)
#define A32c (float)(9.0/40.0)
#define A41c (float)(44.0/45.0)
#define A42c (float)(-56.0/15.0)
#define A43c (float)(32.0/9.0)
#define A51c (float)(19372.0/6561.0)
#define A52c (float)(-25360.0/2187.0)
#define A53c (float)(64448.0/6561.0)
#define A54c (float)(-212.0/729.0)
#define A61c (float)(9017.0/3168.0)
#define A62c (float)(-355.0/33.0)
#define A63c (float)(46732.0/5247.0)
#define A64c (float)(49.0/176.0)
#define A65c (float)(-5103.0/18656.0)
#define B1c  (float)(35.0/384.0)
#define B3c  (float)(500.0/1113.0)
#define B4c  (float)(125.0/192.0)
#define B5c  (float)(-2187.0/6784.0)
#define B6c  (float)(11.0/84.0)

// Zero the segment-sum accumulators in workspace (re-poisoned 0xAA each call).
__global__ void zero_ws_kernel(float4* ws, int n4) {
    int i = blockIdx.x * blockDim.x + threadIdx.x;
    if (i < n4) ws[i] = make_float4(0.f, 0.f, 0.f, 0.f);
}

// Edge phase: encode edges, decode dec_e, scatter-add h_e into sent/recv sums.
__global__ __launch_bounds__(256) void edge_kernel(
    const float* __restrict__ edges,
    const int* __restrict__ senders,
    const int* __restrict__ receivers,
    const float* __restrict__ W,    // (3,10)
    const float* __restrict__ b,    // (10)
    const float* __restrict__ Wd,   // (10,1)
    const float* __restrict__ bd,   // (1)
    float* __restrict__ sent,       // (N_NODES,10) accumulators
    float* __restrict__ recv,       // (N_NODES,10) accumulators
    float* __restrict__ dec_e)      // (N_EDGES)
{
    int e = blockIdx.x * 256 + threadIdx.x;
    if (e >= N_EDGES) return;
    float e0 = edges[e*3+0], e1 = edges[e*3+1], e2 = edges[e*3+2];
    int s = senders[e], r = receivers[e];
    float he[10];
    float d = bd[0];
    #pragma unroll
    for (int j = 0; j < 10; ++j) {
        float v = fmaf(e0, W[j], fmaf(e1, W[10+j], fmaf(e2, W[20+j], b[j])));
        he[j] = v;
        d = fmaf(v, Wd[j], d);
    }
    dec_e[e] = d;
    #pragma unroll
    for (int j = 0; j < 10; ++j) atomicAdd(&sent[s*10+j], he[j]);
    #pragma unroll
    for (int j = 0; j < 10; ++j) atomicAdd(&recv[r*10+j], he[j]);
}

// One derivative eval: out = relu(in @ W1 + b1) @ W2 + b2, all 32-wide.
// W/b in LDS as float4 (uniform-address broadcast reads, conflict-free).
__device__ __forceinline__ void deriv32(const float4* __restrict__ sW1,
                                        const float4* __restrict__ sW2,
                                        const float4* __restrict__ sB,  // [0..7]=b1, [8..15]=b2
                                        const float* __restrict__ in,
                                        float* __restrict__ out)
{
    float t[32];
    #pragma unroll
    for (int j4 = 0; j4 < 8; ++j4) {
        float4 bb = sB[j4];
        t[4*j4+0] = bb.x; t[4*j4+1] = bb.y; t[4*j4+2] = bb.z; t[4*j4+3] = bb.w;
    }
    #pragma unroll
    for (int i = 0; i < 32; ++i) {
        float v = in[i];
        #pragma unroll
        for (int j4 = 0; j4 < 8; ++j4) {
            float4 w = sW1[i*8 + j4];
            t[4*j4+0] = fmaf(v, w.x, t[4*j4+0]);
            t[4*j4+1] = fmaf(v, w.y, t[4*j4+1]);
            t[4*j4+2] = fmaf(v, w.z, t[4*j4+2]);
            t[4*j4+3] = fmaf(v, w.w, t[4*j4+3]);
        }
    }
    #pragma unroll
    for (int j = 0; j < 32; ++j) t[j] = fmaxf(t[j], 0.0f);
    #pragma unroll
    for (int j4 = 0; j4 < 8; ++j4) {
        float4 bb = sB[8 + j4];
        out[4*j4+0] = bb.x; out[4*j4+1] = bb.y; out[4*j4+2] = bb.z; out[4*j4+3] = bb.w;
    }
    #pragma unroll
    for (int i = 0; i < 32; ++i) {
        float v = t[i];
        #pragma unroll
        for (int j4 = 0; j4 < 8; ++j4) {
            float4 w = sW2[i*8 + j4];
            out[4*j4+0] = fmaf(v, w.x, out[4*j4+0]);
            out[4*j4+1] = fmaf(v, w.y, out[4*j4+1]);
            out[4*j4+2] = fmaf(v, w.z, out[4*j4+2]);
            out[4*j4+3] = fmaf(v, w.w, out[4*j4+3]);
        }
    }
}

// Node phase: encode node, assemble x, integrate 10 RK45 steps, decode outputs.
__global__ __launch_bounds__(256, 1) void node_kernel(
    const float* __restrict__ nodes,     // (N_NODES,2)
    const float* __restrict__ globals_,  // (2)
    const float* __restrict__ encW,      // (2,10)
    const float* __restrict__ encb,      // (10)
    const float* __restrict__ W1,        // (32,32)
    const float* __restrict__ b1,        // (32)
    const float* __restrict__ W2,        // (32,32)
    const float* __restrict__ b2,        // (32)
    const float* __restrict__ Wno,       // (32,10)
    const float* __restrict__ bno,       // (10)
    const float* __restrict__ Wdn,       // (10,1)
    const float* __restrict__ bdn,       // (1)
    const float* __restrict__ sent,      // (N_NODES,10)
    const float* __restrict__ recv,      // (N_NODES,10)
    float* __restrict__ out_decn,        // (N_NODES)
    float* __restrict__ out_pos,         // (N_NODES)
    float* __restrict__ out_vel)         // (N_NODES)
{
    __shared__ float4 sW1[256];
    __shared__ float4 sW2[256];
    __shared__ float4 sB[16];
    {
        int t = threadIdx.x;
        sW1[t] = ((const float4*)W1)[t];
        sW2[t] = ((const float4*)W2)[t];
        if (t < 8)  sB[t]     = ((const float4*)b1)[t];
        else if (t < 16) sB[t] = ((const float4*)b2)[t - 8];
    }
    __syncthreads();

    int n = blockIdx.x * 256 + threadIdx.x;
    if (n >= N_NODES) return;

    float pos = nodes[n*2+0];
    float vel = nodes[n*2+1];

    float y[32];
    #pragma unroll
    for (int j = 0; j < 10; ++j)
        y[j] = fmaf(pos, encW[j], fmaf(vel, encW[10+j], encb[j]));
    #pragma unroll
    for (int j = 0; j < 10; ++j) y[10+j] = sent[n*10+j];
    #pragma unroll
    for (int j = 0; j < 10; ++j) y[20+j] = recv[n*10+j];
    y[30] = globals_[0];
    y[31] = globals_[1];

    for (int s = 0; s < 10; ++s) {
        float k1[32], k2[32], k3[32], k4[32], k5[32], k6[32], u[32];
        deriv32(sW1, sW2, sB, y, k1);
        #pragma unroll
        for (int j = 0; j < 32; ++j) u[j] = fmaf(Hc * A21c, k1[j], y[j]);
        deriv32(sW1, sW2, sB, u, k2);
        #pragma unroll
        for (int j = 0; j < 32; ++j)
            u[j] = fmaf(Hc, fmaf(A31c, k1[j], A32c * k2[j]), y[j]);
        deriv32(sW1, sW2, sB, u, k3);
        #pragma unroll
        for (int j = 0; j < 32; ++j)
            u[j] = fmaf(Hc, fmaf(A41c, k1[j], fmaf(A42c, k2[j], A43c * k3[j])), y[j]);
        deriv32(sW1, sW2, sB, u, k4);
        #pragma unroll
        for (int j = 0; j < 32; ++j)
            u[j] = fmaf(Hc, fmaf(A51c, k1[j], fmaf(A52c, k2[j], fmaf(A53c, k3[j], A54c * k4[j]))), y[j]);
        deriv32(sW1, sW2, sB, u, k5);
        #pragma unroll
        for (int j = 0; j < 32; ++j)
            u[j] = fmaf(Hc, fmaf(A61c, k1[j], fmaf(A62c, k2[j], fmaf(A63c, k3[j], fmaf(A64c, k4[j], A65c * k5[j])))), y[j]);
        deriv32(sW1, sW2, sB, u, k6);
        #pragma unroll
        for (int j = 0; j < 32; ++j)
            y[j] = fmaf(Hc, fmaf(B1c, k1[j], fmaf(B3c, k3[j], fmaf(B4c, k4[j], fmaf(B5c, k5[j], B6c * k6[j])))), y[j]);
    }

    // node_out: (32,10), then dec_node: (10,1)
    float h2[10];
    #pragma unroll
    for (int j = 0; j < 10; ++j) h2[j] = bno[j];
    #pragma unroll
    for (int i = 0; i < 32; ++i) {
        float v = y[i];
        #pragma unroll
        for (int j = 0; j < 10; ++j) h2[j] = fmaf(v, Wno[i*10+j], h2[j]);
    }
    float dn = bdn[0];
    #pragma unroll
    for (int j = 0; j < 10; ++j) dn = fmaf(h2[j], Wdn[j], dn);

    out_decn[n] = dn;
    float nv = vel + dn;   // DT = 1
    float np = pos + nv;
    out_pos[n] = np;
    out_vel[n] = nv;
}

extern "C" void kernel_launch(void* const* d_in, const int* in_sizes, int n_in,
                              void* d_out, int out_size, void* d_ws, size_t ws_size,
                              hipStream_t stream) {
    const float* nodes      = (const float*)d_in[0];
    const float* edges      = (const float*)d_in[1];
    const int*   senders    = (const int*)d_in[2];
    const int*   receivers  = (const int*)d_in[3];
    const float* globals_   = (const float*)d_in[4];
    const float* enc_node_W = (const float*)d_in[5];
    const float* enc_node_b = (const float*)d_in[6];
    const float* enc_edge_W = (const float*)d_in[7];
    const float* enc_edge_b = (const float*)d_in[8];
    const float* ode_W1     = (const float*)d_in[9];
    const float* ode_b1     = (const float*)d_in[10];
    const float* ode_W2     = (const float*)d_in[11];
    const float* ode_b2     = (const float*)d_in[12];
    const float* node_out_W = (const float*)d_in[13];
    const float* node_out_b = (const float*)d_in[14];
    const float* dec_node_W = (const float*)d_in[15];
    const float* dec_node_b = (const float*)d_in[16];
    const float* dec_edge_W = (const float*)d_in[17];
    const float* dec_edge_b = (const float*)d_in[18];

    float* out = (float*)d_out;
    float* out_decn = out;                    // [0, 1e5)
    float* out_dece = out + N_NODES;          // [1e5, 1.7e6)
    float* out_pos  = out + N_NODES + N_EDGES;            // [1.7e6, 1.8e6)
    float* out_vel  = out + 2*N_NODES + N_EDGES;          // [1.8e6, 1.9e6)

    float* sent = (float*)d_ws;               // N_NODES*10 floats
    float* recv = sent + N_NODES*10;          // N_NODES*10 floats

    // 1) zero accumulators (2,000,000 floats = 500,000 float4)
    {
        int n4 = (N_NODES * 10 * 2) / 4;
        int blocks = (n4 + 255) / 256;
        zero_ws_kernel<<<blocks, 256, 0, stream>>>((float4*)d_ws, n4);
    }
    // 2) edge phase
    edge_kernel<<<(N_EDGES + 255) / 256, 256, 0, stream>>>(
        edges, senders, receivers, enc_edge_W, enc_edge_b,
        dec_edge_W, dec_edge_b, sent, recv, out_dece);
    // 3) node ODE phase
    node_kernel<<<(N_NODES + 255) / 256, 256, 0, stream>>>(
        nodes, globals_, enc_node_W, enc_node_b,
        ode_W1, ode_b1, ode_W2, ode_b2,
        node_out_W, node_out_b, dec_node_W, dec_node_b,
        sent, recv, out_decn, out_pos, out_vel);
}